// Round 4
// baseline (3125.648 us; speedup 1.0000x reference)
//
#include <hip/hip_runtime.h>
#include <stdint.h>

typedef unsigned short U16;
typedef float f32x4 __attribute__((ext_vector_type(4)));
typedef __bf16 bf16x8 __attribute__((ext_vector_type(8)));

static __device__ __forceinline__ U16 f2bf(float x) {
  union { float f; unsigned u; } v; v.f = x;
  unsigned r = v.u + 0x7FFFu + ((v.u >> 16) & 1u);
  return (U16)(r >> 16);
}
static __device__ __forceinline__ float bf2f(U16 h) {
  union { unsigned u; float f; } v; v.u = ((unsigned)h) << 16;
  return v.f;
}

static __device__ __forceinline__ void gload_lds16(const void* g, void* l) {
  __builtin_amdgcn_global_load_lds(
      (const __attribute__((address_space(1))) void*)g,
      (__attribute__((address_space(3))) void*)l, 16, 0, 0);
}

// flags[0]=detect(1=bf16 in), [1]=chkA fail, [2]=chkB, [3]=chkC, [4]=chkD
__global__ void k_clear(int* __restrict__ flags) {
  if (threadIdx.x < 8) flags[threadIdx.x] = 0;
}

// ---------------- dtype detect: 1 = bf16 inputs, 0 = fp32 inputs ------------
__global__ void k_detect(const unsigned* __restrict__ in, int* __restrict__ flag) {
  __shared__ int cnt;
  if (threadIdx.x == 0) cnt = 0;
  __syncthreads();
  int local = 0;
  for (int i = threadIdx.x; i < 4096; i += 256) {
    unsigned w = in[i];
    unsigned e = (w >> 7) & 0xFFu;
    if (w == 0u || (e >= 100u && e <= 150u)) local++;
  }
  atomicAdd(&cnt, local);
  __syncthreads();
  if (threadIdx.x == 0) *flag = (cnt > 3000) ? 1 : 0;
}

// ---------------- hidden -> bf16 --------------------------------------------
__global__ __launch_bounds__(256) void k_convert(const void* __restrict__ src,
                                                 U16* __restrict__ dst,
                                                 const int* __restrict__ flag, long n) {
  long base = ((long)blockIdx.x * 256 + threadIdx.x) * 8;
  if (base >= n) return;
  if (*flag) {
    *(uint4*)(dst + base) = *(const uint4*)((const U16*)src + base);
  } else {
    const float4* s = (const float4*)((const float*)src + base);
    float4 a = s[0], b = s[1];
    U16 o[8] = { f2bf(a.x), f2bf(a.y), f2bf(a.z), f2bf(a.w),
                 f2bf(b.x), f2bf(b.y), f2bf(b.z), f2bf(b.w) };
    *(uint4*)(dst + base) = *(const uint4*)o;
  }
}

// ---------------- W[K][N] -> Wt[N][K] bf16 ----------------------------------
__global__ __launch_bounds__(256) void k_transpose(const void* __restrict__ src,
                                                   U16* __restrict__ dst,
                                                   int K, int N, const int* __restrict__ flag) {
  __shared__ U16 tile[32][33];
  int n0 = blockIdx.x * 32, k0 = blockIdx.y * 32;
  int tx = threadIdx.x & 31, ty = threadIdx.x >> 5;
  bool isbf = (*flag != 0);
  const U16* sh = (const U16*)src;
  const float* sf = (const float*)src;
#pragma unroll
  for (int r = 0; r < 4; ++r) {
    int k = k0 + ty + r * 8;
    long idx = (long)k * N + n0 + tx;
    tile[ty + r * 8][tx] = isbf ? sh[idx] : f2bf(sf[idx]);
  }
  __syncthreads();
#pragma unroll
  for (int r = 0; r < 4; ++r) {
    int n = n0 + ty + r * 8;
    dst[(long)n * K + k0 + tx] = tile[tx][ty + r * 8];
  }
}

// ---------------- RoPE tables (fp32) ----------------------------------------
__global__ __launch_bounds__(256) void k_rope_tables(float* __restrict__ cosT,
                                                     float* __restrict__ sinT) {
  int i = blockIdx.x * 256 + threadIdx.x;
  int s = i >> 7, d = i & 127;
  float freq = expf(-9.210340371976184f * (float)d / 128.0f);
  float ang = (float)s * freq;
  cosT[i] = cosf(ang);
  sinT[i] = sinf(ang);
}

// ---------------- RoPE in place on q,k sections of QKV ----------------------
__global__ __launch_bounds__(256) void k_rope(U16* __restrict__ qkv,
                                              const float* __restrict__ cosT,
                                              const float* __restrict__ sinT) {
  int i = blockIdx.x * 256 + threadIdx.x;
  int d = i & 127;
  int hh = (i >> 7) % 24;
  int row = i / 3072;
  int s = row & 2047;
  int col = (hh < 16) ? hh * 256 + d : 4096 + (hh - 16) * 256 + d;
  long base = (long)row * 8192 + col;
  float c = cosT[s * 128 + d], sn = sinT[s * 128 + d];
  float x1 = bf2f(qkv[base]), x2 = bf2f(qkv[base + 128]);
  qkv[base]       = f2bf(x1 * c - x2 * sn);
  qkv[base + 128] = f2bf(x2 * c + x1 * sn);
}

// ---------------- GEMM: C[M][N] = A[M][K] * Bt[N][K]^T ----------------------
// F32OUT=0: write bf16 (U16). F32OUT=1: write fp32 (d_out is float*).
template <int F32OUT>
__global__ __launch_bounds__(256) void k_gemm(const U16* __restrict__ A,
                                              const U16* __restrict__ Bt,
                                              void* __restrict__ Cv,
                                              int M, int N, int K) {
  __shared__ __align__(16) U16 As[128 * 32];
  __shared__ __align__(16) U16 Bs[128 * 32];
  int t = threadIdx.x, lane = t & 63, w = t >> 6;
  int m0 = blockIdx.y * 128, n0 = blockIdx.x * 128;
  int wr = (w >> 1) * 64, wc = (w & 1) * 64;
  int l15 = lane & 15, l4 = lane >> 4;
  f32x4 acc[4][4] = {};
  int rowA = t >> 2, colg = (t & 3) * 8;
  const U16* gA0 = A + (long)(m0 + rowA) * K + colg;
  const U16* gA1 = A + (long)(m0 + 64 + rowA) * K + colg;
  const U16* gB0 = Bt + (long)(n0 + rowA) * K + colg;
  const U16* gB1 = Bt + (long)(n0 + 64 + rowA) * K + colg;
  char* lA0 = (char*)As + w * 1024;
  char* lA1 = (char*)As + 4096 + w * 1024;
  char* lB0 = (char*)Bs + w * 1024;
  char* lB1 = (char*)Bs + 4096 + w * 1024;

  for (int k0 = 0; k0 < K; k0 += 32) {
    gload_lds16(gA0 + k0, lA0);
    gload_lds16(gA1 + k0, lA1);
    gload_lds16(gB0 + k0, lB0);
    gload_lds16(gB1 + k0, lB1);
    asm volatile("s_waitcnt vmcnt(0)" ::: "memory");
    __syncthreads();
    bf16x8 af[4], bb[4];
#pragma unroll
    for (int m = 0; m < 4; ++m)
      af[m] = *(const bf16x8*)&As[(wr + m * 16 + l15) * 32 + l4 * 8];
#pragma unroll
    for (int n = 0; n < 4; ++n)
      bb[n] = *(const bf16x8*)&Bs[(wc + n * 16 + l15) * 32 + l4 * 8];
#pragma unroll
    for (int m = 0; m < 4; ++m)
#pragma unroll
      for (int n = 0; n < 4; ++n)
        acc[m][n] = __builtin_amdgcn_mfma_f32_16x16x32_bf16(af[m], bb[n], acc[m][n], 0, 0, 0);
    __syncthreads();
  }
#pragma unroll
  for (int m = 0; m < 4; ++m)
#pragma unroll
    for (int jj = 0; jj < 4; ++jj) {
      int row = m0 + wr + m * 16 + l4 * 4 + jj;
      if (F32OUT) {
        float* cp = (float*)Cv + (long)row * N + n0 + wc + l15;
#pragma unroll
        for (int n = 0; n < 4; ++n) cp[n * 16] = acc[m][n][jj];
      } else {
        U16* cp = (U16*)Cv + (long)row * N + n0 + wc + l15;
#pragma unroll
        for (int n = 0; n < 4; ++n) cp[n * 16] = f2bf(acc[m][n][jj]);
      }
    }
}

// ---------------- banded GQA attention (unchanged, verified by chkC) --------
__global__ __launch_bounds__(256) void k_attn(const U16* __restrict__ QKV,
                                              U16* __restrict__ O) {
  __shared__ __align__(16) U16 Ks[32 * 264];
  __shared__ __align__(16) U16 Vt[256 * 40];
  __shared__ __align__(16) float Sb[4][16 * 36];
  __shared__ __align__(16) U16 Plds[4][16 * 40];
  __shared__ float EscB[4][16];
  __shared__ float LrB[4][16];

  int t = threadIdx.x, lane = t & 63, w = t >> 6;
  int qb = blockIdx.x, h = blockIdx.y, b = blockIdx.z;
  int s0 = qb * 64;
  int kvh = h >> 1;
  long rowOff = (long)b * 2048 * 8192;
  const U16* Qb = QKV + rowOff + h * 256;
  const U16* Kb = QKV + rowOff + 4096 + kvh * 256;
  const U16* Vb = QKV + rowOff + 6144 + kvh * 256;

  int l15 = lane & 15, l4 = lane >> 4;

  bf16x8 qf[8];
  {
    const U16* qp = Qb + (long)(s0 + w * 16 + l15) * 8192 + l4 * 8;
#pragma unroll
    for (int kc = 0; kc < 8; ++kc) qf[kc] = *(const bf16x8*)(qp + kc * 32);
  }
  f32x4 acc[16] = {};
  float mrun = -1e30f, lrun = 0.0f;
  int qpos = s0 + w * 16 + l15;

  int kstart = s0 - 1024; if (kstart < 0) kstart = 0;
  int kend = s0 + 64 + 1024; if (kend > 2048) kend = 2048;

  int kkey = t >> 3, kc8 = t & 7;
  int vkey = t & 31, vd8 = (t >> 5) * 32;

  for (int k0 = kstart; k0 < kend; k0 += 32) {
    uint4 kr[4];
    {
      const U16* kp = Kb + (long)(k0 + kkey) * 8192 + kc8 * 32;
#pragma unroll
      for (int i = 0; i < 4; ++i) kr[i] = *(const uint4*)(kp + i * 8);
    }
    union { uint4 q; U16 s[8]; } vr[4];
    {
      const U16* vp = Vb + (long)(k0 + vkey) * 8192 + vd8;
#pragma unroll
      for (int i = 0; i < 4; ++i) vr[i].q = *(const uint4*)(vp + i * 8);
    }
    __syncthreads();
#pragma unroll
    for (int i = 0; i < 4; ++i)
      *(uint4*)&Ks[kkey * 264 + kc8 * 32 + i * 8] = kr[i];
#pragma unroll
    for (int i = 0; i < 4; ++i)
#pragma unroll
      for (int m = 0; m < 8; ++m)
        Vt[(vd8 + i * 8 + m) * 40 + vkey] = vr[i].s[m];
    __syncthreads();

    f32x4 sAcc[2] = {};
#pragma unroll
    for (int kc = 0; kc < 8; ++kc)
#pragma unroll
      for (int mp = 0; mp < 2; ++mp) {
        int key = mp * 16 + l15;
        bf16x8 ak = *(const bf16x8*)&Ks[key * 264 + (kc * 4 + l4) * 8];
        sAcc[mp] = __builtin_amdgcn_mfma_f32_16x16x32_bf16(ak, qf[kc], sAcc[mp], 0, 0, 0);
      }
    float sv[8];
#pragma unroll
    for (int mp = 0; mp < 2; ++mp)
#pragma unroll
      for (int jj = 0; jj < 4; ++jj) {
        int keyl = mp * 16 + l4 * 4 + jj;
        int key = k0 + keyl;
        float x = sAcc[mp][jj] * 0.0625f * 0.02f;
        float ex = __expf(2.0f * x);
        float z = 50.0f * (ex - 1.0f) / (ex + 1.0f);
        int dd = qpos - key;
        if (dd < -1024 || dd > 1024) z = -3e38f;
        sv[mp * 4 + jj] = z;
        Sb[w][l15 * 36 + keyl] = z;
      }
    asm volatile("s_waitcnt lgkmcnt(0)" ::: "memory");
    __builtin_amdgcn_sched_barrier(0);
    float m_tile = -3e38f;
#pragma unroll
    for (int g = 0; g < 8; ++g) {
      f32x4 rv = *(const f32x4*)&Sb[w][l15 * 36 + g * 4];
      m_tile = fmaxf(m_tile, fmaxf(fmaxf(rv[0], rv[1]), fmaxf(rv[2], rv[3])));
    }
    float mnew = fmaxf(mrun, m_tile);
    float esc = __expf(mrun - mnew);
    float psum = 0.0f;
#pragma unroll
    for (int g = 0; g < 8; ++g) {
      f32x4 rv = *(const f32x4*)&Sb[w][l15 * 36 + g * 4];
      psum += __expf(rv[0] - mnew) + __expf(rv[1] - mnew) +
              __expf(rv[2] - mnew) + __expf(rv[3] - mnew);
    }
    lrun = lrun * esc + psum;
    mrun = mnew;
#pragma unroll
    for (int mp = 0; mp < 2; ++mp)
#pragma unroll
      for (int jj = 0; jj < 4; ++jj) {
        int keyl = mp * 16 + l4 * 4 + jj;
        Plds[w][l15 * 40 + keyl] = f2bf(__expf(sv[mp * 4 + jj] - mnew));
      }
    if (l4 == 0) EscB[w][l15] = esc;
    asm volatile("s_waitcnt lgkmcnt(0)" ::: "memory");
    __builtin_amdgcn_sched_barrier(0);
    f32x4 escv;
#pragma unroll
    for (int jj = 0; jj < 4; ++jj) escv[jj] = EscB[w][l4 * 4 + jj];
#pragma unroll
    for (int n = 0; n < 16; ++n) acc[n] *= escv;
    bf16x8 pa = *(const bf16x8*)&Plds[w][l15 * 40 + l4 * 8];
#pragma unroll
    for (int n = 0; n < 16; ++n) {
      int d = n * 16 + l15;
      bf16x8 vb = *(const bf16x8*)&Vt[d * 40 + l4 * 8];
      acc[n] = __builtin_amdgcn_mfma_f32_16x16x32_bf16(pa, vb, acc[n], 0, 0, 0);
    }
  }
  if (l4 == 0) LrB[w][l15] = lrun;
  asm volatile("s_waitcnt lgkmcnt(0)" ::: "memory");
  __builtin_amdgcn_sched_barrier(0);
  f32x4 linv;
#pragma unroll
  for (int jj = 0; jj < 4; ++jj) linv[jj] = 1.0f / LrB[w][l4 * 4 + jj];
#pragma unroll
  for (int jj = 0; jj < 4; ++jj) {
    int row = s0 + w * 16 + l4 * 4 + jj;
    U16* op = O + ((long)b * 2048 + row) * 4096 + h * 256 + l15;
#pragma unroll
    for (int n = 0; n < 16; ++n) op[n * 16] = f2bf(acc[n][jj] * linv[jj]);
  }
}

// =================== ON-DEVICE SCALAR CHECKERS ==============================
__global__ void k_chkA(const float* hid, const float* Wq, const float* Wk,
                       const float* Wv, const U16* Xb, const U16* Wt,
                       int* flags) {
  if (flags[0] != 0) return;
  int t = blockIdx.x * 256 + threadIdx.x;
  int bad = 0;
  for (int j = 0; j < 4; ++j) {
    long sidx = t * 4 + j;
    long i = (sidx * 14669) % ((long)4096 * 3584);
    if (Xb[i] != f2bf(hid[i])) bad = 1;
    int k = (int)((sidx * 131) % 3584);
    int n = (int)((sidx * 277) % 4096);
    int n2 = (int)((sidx * 277) % 2048);
    if (Wt[(long)n * 3584 + k] != f2bf(Wq[(long)k * 4096 + n])) bad = 1;
    if (Wt[(long)(4096 + n2) * 3584 + k] != f2bf(Wk[(long)k * 2048 + n2])) bad = 1;
    if (Wt[(long)(6144 + n2) * 3584 + k] != f2bf(Wv[(long)k * 2048 + n2])) bad = 1;
  }
  if (bad) atomicOr(&flags[1], 1);
}

__global__ void k_chkB(const U16* Xb, const U16* Wt, const U16* QKV,
                       const float* cosT, const float* sinT, int* flags) {
  int t = blockIdx.x * 256 + threadIdx.x;
  long sidx = t;
  int row = (int)((sidx * 2003) & 4095);
  int col = (int)((sidx * 4999) & 8191);
  float dot = 0.0f, dotp = 0.0f;
  bool rope = col < 6144;
  int d256 = col & 255;
  int partner = rope ? (d256 < 128 ? col + 128 : col - 128) : 0;
  const U16* xr = Xb + (long)row * 3584;
  const U16* wr = Wt + (long)col * 3584;
  const U16* wp = Wt + (long)partner * 3584;
  for (int e = 0; e < 3584; ++e) {
    float xv = bf2f(xr[e]);
    dot = fmaf(xv, bf2f(wr[e]), dot);
    if (rope) dotp = fmaf(xv, bf2f(wp[e]), dotp);
  }
  float val = dot;
  if (rope) {
    int s = row & 2047;
    float c = cosT[s * 128 + (d256 & 127)];
    float sn = sinT[s * 128 + (d256 & 127)];
    val = (d256 < 128) ? (dot * c - dotp * sn) : (dot * c + dotp * sn);
  }
  float got = bf2f(QKV[(long)row * 8192 + col]);
  if (fabsf(got - val) > 0.08f + 0.05f * fabsf(val)) atomicOr(&flags[2], 1);
}

__global__ void k_chkC(const U16* QKV, const U16* AttO, int* flags) {
  __shared__ float S[2048];
  __shared__ float ml[2];
  const int smp[4][3] = {{0, 0, 100}, {0, 7, 1500}, {1, 10, 2000}, {1, 15, 3}};
  int b = smp[blockIdx.x][0], h = smp[blockIdx.x][1], q = smp[blockIdx.x][2];
  int kvh = h >> 1;
  long base = (long)b * 2048 * 8192;
  const U16* Q = QKV + base + (long)q * 8192 + h * 256;
  int ks = q - 1024; if (ks < 0) ks = 0;
  int ke = q + 1025; if (ke > 2048) ke = 2048;
  for (int key = threadIdx.x; key < 2048; key += 256) {
    float sc = -3e38f;
    if (key >= ks && key < ke) {
      const U16* K = QKV + base + (long)key * 8192 + 4096 + kvh * 256;
      float a = 0.0f;
      for (int d = 0; d < 256; ++d) a = fmaf(bf2f(Q[d]), bf2f(K[d]), a);
      float xx = a * 0.0625f * 0.02f;
      float ex = __expf(2.0f * xx);
      sc = 50.0f * (ex - 1.0f) / (ex + 1.0f);
    }
    S[key] = sc;
  }
  __syncthreads();
  if (threadIdx.x == 0) {
    float m = -3e38f;
    for (int k2 = ks; k2 < ke; ++k2) m = fmaxf(m, S[k2]);
    float l = 0.0f;
    for (int k2 = ks; k2 < ke; ++k2) l += __expf(S[k2] - m);
    ml[0] = m; ml[1] = l;
  }
  __syncthreads();
  int d = threadIdx.x;
  float m = ml[0], l = ml[1];
  float o = 0.0f;
  for (int key = ks; key < ke; ++key)
    o = fmaf(__expf(S[key] - m),
             bf2f(QKV[base + (long)key * 8192 + 6144 + kvh * 256 + d]), o);
  o /= l;
  float got = bf2f(AttO[((long)b * 2048 + q) * 4096 + h * 256 + d]);
  if (fabsf(got - o) > 0.04f + 0.05f * fabsf(o)) atomicOr(&flags[3], 1);
}

// chkD: d_out (fp32 now) vs scalar AttO·Wot dots; Wot vs f2bf(Wo) exact.
__global__ void k_chkD(const U16* AttO, const U16* Wot, const float* Wo,
                       const float* out, const int* __restrict__ dflag, int* flags) {
  int t = blockIdx.x * 256 + threadIdx.x;
  long sidx = t;
  int row = (int)((sidx * 2003) & 4095);
  int col = (int)((sidx * 757) % 3584);
  if (dflag[0] == 0) {
    int k2 = (int)((sidx * 443) & 4095);
    if (Wot[(long)col * 4096 + k2] != f2bf(Wo[(long)k2 * 3584 + col]))
      atomicOr(&flags[4], 1);
  }
  float val = 0.0f;
  const U16* ar = AttO + (long)row * 4096;
  const U16* wr = Wot + (long)col * 4096;
  for (int k = 0; k < 4096; ++k) val = fmaf(bf2f(ar[k]), bf2f(wr[k]), val);
  float got = out[(long)row * 3584 + col];
  if (fabsf(got - val) > 0.08f + 0.05f * fabsf(val)) atomicOr(&flags[4], 1);
}

// encode first failing stage into d_out[0..15] as fp32 code*1e6
__global__ void k_encode(const int* __restrict__ flags, float* __restrict__ out) {
  if (threadIdx.x == 0 && blockIdx.x == 0) {
    int code = 0;
    if (flags[0] == 1) code = 5;
    else if (flags[1]) code = 1;
    else if (flags[2]) code = 2;
    else if (flags[3]) code = 3;
    else if (flags[4]) code = 4;
    if (code) {
      float v = 1.0e6f * (float)code;
      for (int i = 0; i < 16; ++i) out[i] = v;
    }
  }
}

// ----------------------------------------------------------------------------
extern "C" void kernel_launch(void* const* d_in, const int* in_sizes, int n_in,
                              void* d_out, int out_size, void* d_ws, size_t ws_size,
                              hipStream_t stream) {
  if (n_in < 5) return;
  const void* hid = d_in[0];
  const void* Wq  = d_in[1];
  const void* Wk  = d_in[2];
  const void* Wv  = d_in[3];
  const void* Wo  = d_in[4];

  char* ws = (char*)d_ws;
  size_t off = 0;
  auto alloc = [&](size_t bytes) {
    char* p = ws + off;
    off += (bytes + 255) & ~(size_t)255;
    return p;
  };
  int*   flags = (int*)alloc(256);
  float* cosT = (float*)alloc((size_t)2048 * 128 * 4);
  float* sinT = (float*)alloc((size_t)2048 * 128 * 4);
  U16*   Xb   = (U16*)alloc((size_t)4096 * 3584 * 2);   // later reused as Wot
  U16*   Wt   = (U16*)alloc((size_t)8192 * 3584 * 2);   // later reused as AttO
  U16*   QKV  = (U16*)alloc((size_t)4096 * 8192 * 2);
  if (off > ws_size) return;
  U16* Wot  = Xb;
  U16* AttO = Wt;

  k_clear<<<1, 64, 0, stream>>>(flags);
  k_detect<<<1, 256, 0, stream>>>((const unsigned*)hid, flags);
  k_convert<<<7168, 256, 0, stream>>>(hid, Xb, flags, (long)4096 * 3584);
  k_transpose<<<dim3(128, 112), 256, 0, stream>>>(Wq, Wt, 3584, 4096, flags);
  k_transpose<<<dim3(64, 112), 256, 0, stream>>>(Wk, Wt + (size_t)4096 * 3584, 3584, 2048, flags);
  k_transpose<<<dim3(64, 112), 256, 0, stream>>>(Wv, Wt + (size_t)6144 * 3584, 3584, 2048, flags);
  k_chkA<<<4, 256, 0, stream>>>((const float*)hid, (const float*)Wq, (const float*)Wk,
                                (const float*)Wv, Xb, Wt, flags);
  k_rope_tables<<<1024, 256, 0, stream>>>(cosT, sinT);
  k_gemm<0><<<dim3(64, 32), 256, 0, stream>>>(Xb, Wt, QKV, 4096, 8192, 3584);
  k_rope<<<49152, 256, 0, stream>>>(QKV, cosT, sinT);
  k_chkB<<<4, 256, 0, stream>>>(Xb, Wt, QKV, cosT, sinT, flags);
  k_transpose<<<dim3(112, 128), 256, 0, stream>>>(Wo, Wot, 4096, 3584, flags);
  k_attn<<<dim3(32, 16, 2), 256, 0, stream>>>(QKV, AttO);
  k_chkC<<<4, 256, 0, stream>>>(QKV, AttO, flags);
  k_gemm<1><<<dim3(28, 32), 256, 0, stream>>>(AttO, Wot, d_out, 4096, 3584, 4096);
  k_chkD<<<4, 256, 0, stream>>>(AttO, Wot, (const float*)Wo, (const float*)d_out, flags, flags);
  k_encode<<<1, 64, 0, stream>>>(flags, (float*)d_out);
}

// Round 5
// 1093.864 us; speedup vs baseline: 2.8574x; 2.8574x over previous
//
#include <hip/hip_runtime.h>
#include <stdint.h>

typedef unsigned short U16;
typedef float f32x4 __attribute__((ext_vector_type(4)));
typedef __bf16 bf16x8 __attribute__((ext_vector_type(8)));

static __device__ __forceinline__ U16 f2bf(float x) {
  union { float f; unsigned u; } v; v.f = x;
  unsigned r = v.u + 0x7FFFu + ((v.u >> 16) & 1u);
  return (U16)(r >> 16);
}
static __device__ __forceinline__ float bf2f(U16 h) {
  union { unsigned u; float f; } v; v.u = ((unsigned)h) << 16;
  return v.f;
}

static __device__ __forceinline__ void gload_lds16(const void* g, void* l) {
  __builtin_amdgcn_global_load_lds(
      (const __attribute__((address_space(1))) void*)g,
      (__attribute__((address_space(3))) void*)l, 16, 0, 0);
}

// ---------------- hidden (fp32) -> bf16 -------------------------------------
__global__ __launch_bounds__(256) void k_convert(const float* __restrict__ src,
                                                 U16* __restrict__ dst, long n) {
  long base = ((long)blockIdx.x * 256 + threadIdx.x) * 8;
  if (base >= n) return;
  const float4* s = (const float4*)(src + base);
  float4 a = s[0], b = s[1];
  U16 o[8] = { f2bf(a.x), f2bf(a.y), f2bf(a.z), f2bf(a.w),
               f2bf(b.x), f2bf(b.y), f2bf(b.z), f2bf(b.w) };
  *(uint4*)(dst + base) = *(const uint4*)o;
}

// ---------------- W[K][N] (fp32) -> Wt[N][K] bf16 ----------------------------
__global__ __launch_bounds__(256) void k_transpose(const float* __restrict__ src,
                                                   U16* __restrict__ dst,
                                                   int K, int N) {
  __shared__ U16 tile[32][33];
  int n0 = blockIdx.x * 32, k0 = blockIdx.y * 32;
  int tx = threadIdx.x & 31, ty = threadIdx.x >> 5;
#pragma unroll
  for (int r = 0; r < 4; ++r) {
    int k = k0 + ty + r * 8;
    tile[ty + r * 8][tx] = f2bf(src[(long)k * N + n0 + tx]);
  }
  __syncthreads();
#pragma unroll
  for (int r = 0; r < 4; ++r) {
    int n = n0 + ty + r * 8;
    dst[(long)n * K + k0 + tx] = tile[tx][ty + r * 8];
  }
}

// ---------------- RoPE tables (fp32) ----------------------------------------
__global__ __launch_bounds__(256) void k_rope_tables(float* __restrict__ cosT,
                                                     float* __restrict__ sinT) {
  int i = blockIdx.x * 256 + threadIdx.x;
  int s = i >> 7, d = i & 127;
  float freq = expf(-9.210340371976184f * (float)d / 128.0f);
  float ang = (float)s * freq;
  cosT[i] = cosf(ang);
  sinT[i] = sinf(ang);
}

// ---------------- RoPE in place on q,k sections of QKV ----------------------
__global__ __launch_bounds__(256) void k_rope(U16* __restrict__ qkv,
                                              const float* __restrict__ cosT,
                                              const float* __restrict__ sinT) {
  int i = blockIdx.x * 256 + threadIdx.x;
  int d = i & 127;
  int hh = (i >> 7) % 24;
  int row = i / 3072;
  int s = row & 2047;
  int col = (hh < 16) ? hh * 256 + d : 4096 + (hh - 16) * 256 + d;
  long base = (long)row * 8192 + col;
  float c = cosT[s * 128 + d], sn = sinT[s * 128 + d];
  float x1 = bf2f(qkv[base]), x2 = bf2f(qkv[base + 128]);
  qkv[base]       = f2bf(x1 * c - x2 * sn);
  qkv[base + 128] = f2bf(x2 * c + x1 * sn);
}

// ---------------- GEMM: C[M][N] = A[M][K] * Bt[N][K]^T ----------------------
// F32OUT=0: write bf16 (U16). F32OUT=1: write fp32 (d_out is float*).
template <int F32OUT>
__global__ __launch_bounds__(256) void k_gemm(const U16* __restrict__ A,
                                              const U16* __restrict__ Bt,
                                              void* __restrict__ Cv,
                                              int M, int N, int K) {
  __shared__ __align__(16) U16 As[128 * 32];
  __shared__ __align__(16) U16 Bs[128 * 32];
  int t = threadIdx.x, lane = t & 63, w = t >> 6;
  int m0 = blockIdx.y * 128, n0 = blockIdx.x * 128;
  int wr = (w >> 1) * 64, wc = (w & 1) * 64;
  int l15 = lane & 15, l4 = lane >> 4;
  f32x4 acc[4][4] = {};
  int rowA = t >> 2, colg = (t & 3) * 8;
  const U16* gA0 = A + (long)(m0 + rowA) * K + colg;
  const U16* gA1 = A + (long)(m0 + 64 + rowA) * K + colg;
  const U16* gB0 = Bt + (long)(n0 + rowA) * K + colg;
  const U16* gB1 = Bt + (long)(n0 + 64 + rowA) * K + colg;
  char* lA0 = (char*)As + w * 1024;
  char* lA1 = (char*)As + 4096 + w * 1024;
  char* lB0 = (char*)Bs + w * 1024;
  char* lB1 = (char*)Bs + 4096 + w * 1024;

  for (int k0 = 0; k0 < K; k0 += 32) {
    gload_lds16(gA0 + k0, lA0);
    gload_lds16(gA1 + k0, lA1);
    gload_lds16(gB0 + k0, lB0);
    gload_lds16(gB1 + k0, lB1);
    asm volatile("s_waitcnt vmcnt(0)" ::: "memory");
    __syncthreads();
    bf16x8 af[4], bb[4];
#pragma unroll
    for (int m = 0; m < 4; ++m)
      af[m] = *(const bf16x8*)&As[(wr + m * 16 + l15) * 32 + l4 * 8];
#pragma unroll
    for (int n = 0; n < 4; ++n)
      bb[n] = *(const bf16x8*)&Bs[(wc + n * 16 + l15) * 32 + l4 * 8];
#pragma unroll
    for (int m = 0; m < 4; ++m)
#pragma unroll
      for (int n = 0; n < 4; ++n)
        acc[m][n] = __builtin_amdgcn_mfma_f32_16x16x32_bf16(af[m], bb[n], acc[m][n], 0, 0, 0);
    __syncthreads();
  }
#pragma unroll
  for (int m = 0; m < 4; ++m)
#pragma unroll
    for (int jj = 0; jj < 4; ++jj) {
      int row = m0 + wr + m * 16 + l4 * 4 + jj;
      if (F32OUT) {
        float* cp = (float*)Cv + (long)row * N + n0 + wc + l15;
#pragma unroll
        for (int n = 0; n < 4; ++n) cp[n * 16] = acc[m][n][jj];
      } else {
        U16* cp = (U16*)Cv + (long)row * N + n0 + wc + l15;
#pragma unroll
        for (int n = 0; n < 4; ++n) cp[n * 16] = f2bf(acc[m][n][jj]);
      }
    }
}

// ---------------- banded GQA attention --------------------------------------
__global__ __launch_bounds__(256) void k_attn(const U16* __restrict__ QKV,
                                              U16* __restrict__ O) {
  __shared__ __align__(16) U16 Ks[32 * 264];
  __shared__ __align__(16) U16 Vt[256 * 40];
  __shared__ __align__(16) float Sb[4][16 * 36];
  __shared__ __align__(16) U16 Plds[4][16 * 40];
  __shared__ float EscB[4][16];
  __shared__ float LrB[4][16];

  int t = threadIdx.x, lane = t & 63, w = t >> 6;
  int qb = blockIdx.x, h = blockIdx.y, b = blockIdx.z;
  int s0 = qb * 64;
  int kvh = h >> 1;
  long rowOff = (long)b * 2048 * 8192;
  const U16* Qb = QKV + rowOff + h * 256;
  const U16* Kb = QKV + rowOff + 4096 + kvh * 256;
  const U16* Vb = QKV + rowOff + 6144 + kvh * 256;

  int l15 = lane & 15, l4 = lane >> 4;

  bf16x8 qf[8];
  {
    const U16* qp = Qb + (long)(s0 + w * 16 + l15) * 8192 + l4 * 8;
#pragma unroll
    for (int kc = 0; kc < 8; ++kc) qf[kc] = *(const bf16x8*)(qp + kc * 32);
  }
  f32x4 acc[16] = {};
  float mrun = -1e30f, lrun = 0.0f;
  int qpos = s0 + w * 16 + l15;

  int kstart = s0 - 1024; if (kstart < 0) kstart = 0;
  int kend = s0 + 64 + 1024; if (kend > 2048) kend = 2048;

  int kkey = t >> 3, kc8 = t & 7;
  int vkey = t & 31, vd8 = (t >> 5) * 32;

  for (int k0 = kstart; k0 < kend; k0 += 32) {
    uint4 kr[4];
    {
      const U16* kp = Kb + (long)(k0 + kkey) * 8192 + kc8 * 32;
#pragma unroll
      for (int i = 0; i < 4; ++i) kr[i] = *(const uint4*)(kp + i * 8);
    }
    union { uint4 q; U16 s[8]; } vr[4];
    {
      const U16* vp = Vb + (long)(k0 + vkey) * 8192 + vd8;
#pragma unroll
      for (int i = 0; i < 4; ++i) vr[i].q = *(const uint4*)(vp + i * 8);
    }
    __syncthreads();
#pragma unroll
    for (int i = 0; i < 4; ++i)
      *(uint4*)&Ks[kkey * 264 + kc8 * 32 + i * 8] = kr[i];
#pragma unroll
    for (int i = 0; i < 4; ++i)
#pragma unroll
      for (int m = 0; m < 8; ++m)
        Vt[(vd8 + i * 8 + m) * 40 + vkey] = vr[i].s[m];
    __syncthreads();

    f32x4 sAcc[2] = {};
#pragma unroll
    for (int kc = 0; kc < 8; ++kc)
#pragma unroll
      for (int mp = 0; mp < 2; ++mp) {
        int key = mp * 16 + l15;
        bf16x8 ak = *(const bf16x8*)&Ks[key * 264 + (kc * 4 + l4) * 8];
        sAcc[mp] = __builtin_amdgcn_mfma_f32_16x16x32_bf16(ak, qf[kc], sAcc[mp], 0, 0, 0);
      }
    float sv[8];
#pragma unroll
    for (int mp = 0; mp < 2; ++mp)
#pragma unroll
      for (int jj = 0; jj < 4; ++jj) {
        int keyl = mp * 16 + l4 * 4 + jj;
        int key = k0 + keyl;
        float x = sAcc[mp][jj] * 0.0625f * 0.02f;
        float ex = __expf(2.0f * x);
        float z = 50.0f * (ex - 1.0f) / (ex + 1.0f);
        int dd = qpos - key;
        if (dd < -1024 || dd > 1024) z = -3e38f;
        sv[mp * 4 + jj] = z;
        Sb[w][l15 * 36 + keyl] = z;
      }
    asm volatile("s_waitcnt lgkmcnt(0)" ::: "memory");
    __builtin_amdgcn_sched_barrier(0);
    float m_tile = -3e38f;
#pragma unroll
    for (int g = 0; g < 8; ++g) {
      f32x4 rv = *(const f32x4*)&Sb[w][l15 * 36 + g * 4];
      m_tile = fmaxf(m_tile, fmaxf(fmaxf(rv[0], rv[1]), fmaxf(rv[2], rv[3])));
    }
    float mnew = fmaxf(mrun, m_tile);
    float esc = __expf(mrun - mnew);
    float psum = 0.0f;
#pragma unroll
    for (int g = 0; g < 8; ++g) {
      f32x4 rv = *(const f32x4*)&Sb[w][l15 * 36 + g * 4];
      psum += __expf(rv[0] - mnew) + __expf(rv[1] - mnew) +
              __expf(rv[2] - mnew) + __expf(rv[3] - mnew);
    }
    lrun = lrun * esc + psum;
    mrun = mnew;
#pragma unroll
    for (int mp = 0; mp < 2; ++mp)
#pragma unroll
      for (int jj = 0; jj < 4; ++jj) {
        int keyl = mp * 16 + l4 * 4 + jj;
        Plds[w][l15 * 40 + keyl] = f2bf(__expf(sv[mp * 4 + jj] - mnew));
      }
    if (l4 == 0) EscB[w][l15] = esc;
    asm volatile("s_waitcnt lgkmcnt(0)" ::: "memory");
    __builtin_amdgcn_sched_barrier(0);
    f32x4 escv;
#pragma unroll
    for (int jj = 0; jj < 4; ++jj) escv[jj] = EscB[w][l4 * 4 + jj];
#pragma unroll
    for (int n = 0; n < 16; ++n) acc[n] *= escv;
    bf16x8 pa = *(const bf16x8*)&Plds[w][l15 * 40 + l4 * 8];
#pragma unroll
    for (int n = 0; n < 16; ++n) {
      int d = n * 16 + l15;
      bf16x8 vb = *(const bf16x8*)&Vt[d * 40 + l4 * 8];
      acc[n] = __builtin_amdgcn_mfma_f32_16x16x32_bf16(pa, vb, acc[n], 0, 0, 0);
    }
  }
  if (l4 == 0) LrB[w][l15] = lrun;
  asm volatile("s_waitcnt lgkmcnt(0)" ::: "memory");
  __builtin_amdgcn_sched_barrier(0);
  f32x4 linv;
#pragma unroll
  for (int jj = 0; jj < 4; ++jj) linv[jj] = 1.0f / LrB[w][l4 * 4 + jj];
#pragma unroll
  for (int jj = 0; jj < 4; ++jj) {
    int row = s0 + w * 16 + l4 * 4 + jj;
    U16* op = O + ((long)b * 2048 + row) * 4096 + h * 256 + l15;
#pragma unroll
    for (int n = 0; n < 16; ++n) op[n * 16] = f2bf(acc[n][jj] * linv[jj]);
  }
}

// ----------------------------------------------------------------------------
extern "C" void kernel_launch(void* const* d_in, const int* in_sizes, int n_in,
                              void* d_out, int out_size, void* d_ws, size_t ws_size,
                              hipStream_t stream) {
  if (n_in < 5) return;
  const float* hid = (const float*)d_in[0];
  const float* Wq  = (const float*)d_in[1];
  const float* Wk  = (const float*)d_in[2];
  const float* Wv  = (const float*)d_in[3];
  const float* Wo  = (const float*)d_in[4];

  char* ws = (char*)d_ws;
  size_t off = 0;
  auto alloc = [&](size_t bytes) {
    char* p = ws + off;
    off += (bytes + 255) & ~(size_t)255;
    return p;
  };
  float* cosT = (float*)alloc((size_t)2048 * 128 * 4);
  float* sinT = (float*)alloc((size_t)2048 * 128 * 4);
  U16*   Xb   = (U16*)alloc((size_t)4096 * 3584 * 2);   // later reused as Wot
  U16*   Wt   = (U16*)alloc((size_t)8192 * 3584 * 2);   // later reused as AttO
  U16*   QKV  = (U16*)alloc((size_t)4096 * 8192 * 2);
  if (off > ws_size) return;
  U16* Wot  = Xb;
  U16* AttO = Wt;

  k_convert<<<7168, 256, 0, stream>>>(hid, Xb, (long)4096 * 3584);
  k_transpose<<<dim3(128, 112), 256, 0, stream>>>(Wq, Wt, 3584, 4096);
  k_transpose<<<dim3(64, 112), 256, 0, stream>>>(Wk, Wt + (size_t)4096 * 3584, 3584, 2048);
  k_transpose<<<dim3(64, 112), 256, 0, stream>>>(Wv, Wt + (size_t)6144 * 3584, 3584, 2048);
  k_rope_tables<<<1024, 256, 0, stream>>>(cosT, sinT);
  k_gemm<0><<<dim3(64, 32), 256, 0, stream>>>(Xb, Wt, QKV, 4096, 8192, 3584);
  k_rope<<<49152, 256, 0, stream>>>(QKV, cosT, sinT);
  k_transpose<<<dim3(112, 128), 256, 0, stream>>>(Wo, Wot, 4096, 3584);
  k_attn<<<dim3(32, 16, 2), 256, 0, stream>>>(QKV, AttO);
  k_gemm<1><<<dim3(28, 32), 256, 0, stream>>>(AttO, Wot, d_out, 4096, 3584, 4096);
}